// Round 8
// baseline (147.865 us; speedup 1.0000x reference)
//
#include <hip/hip_runtime.h>
#include <cstdint>

// EdgeConv on MI355X.
// msg_e = A[dst] + B[src], A = x@(W1-W2)+b, B = x@W2.
// agg[i] = A[i] + max_{e: dst=i} B[src_e];  out = relu(agg), 0 for isolated nodes.
// GEMM: bf16x3 MFMA (fp32-level accuracy), W converted in-block.  [proven R7]
// Segment-max via COARSE BUCKETS (16 nodes each): tiny LDS everywhere, full
// occupancy (R7 post-mortem: 40-80KB LDS tables -> 0.5 blk/CU was the cost).
// Per-bucket max kernel: monotonic-u32 keys + LDS atomicMax (2-way bank only).

#define C_CH 128
#define HBLK 256          // histogram/scatter blocks
#define BSH 4             // nodes per bucket = 16
#define BPAD 640          // padded bucket count (>= NBq, stride of T2 rows)

typedef __attribute__((ext_vector_type(8))) short bf16x8;
typedef __attribute__((ext_vector_type(4))) float f32x4;

static inline size_t align_up(size_t v, size_t a) { return (v + a - 1) & ~(a - 1); }

__device__ inline unsigned f2bf_bits(float f) {  // RNE float->bf16 bits
    unsigned u = __builtin_bit_cast(unsigned, f);
    return (u + 0x7FFFu + ((u >> 16) & 1u)) >> 16;
}
__device__ inline unsigned mono_key(unsigned u) {  // order-preserving f32->u32
    return (u & 0x80000000u) ? ~u : (u | 0x80000000u);
}

// ---- K1: MFMA GEMM. Aarr[N][128] = x@(W1-W2)+b (fp32), Bbf[N][128] = bf16(x@W2).
__global__ __launch_bounds__(256) void gemm_mfma(const float* __restrict__ x,
                                                 const float* __restrict__ W,
                                                 const float* __restrict__ bias,
                                                 float* __restrict__ Aarr,
                                                 unsigned short* __restrict__ Bbf,
                                                 int Nn) {
    __shared__ unsigned short Wh[64][136];
    __shared__ unsigned short Wl[64][136];
    int tid = threadIdx.x;
    int col0 = blockIdx.y * 64;
    bool isA = (col0 < C_CH);  // block-uniform
    for (int idx = tid; idx < 64 * 64; idx += 256) {
        int c = idx & 63, k = (idx >> 6) * 2;
        int gc = col0 + c;
        float w0, w1;
        if (isA) {
            w0 = W[k * C_CH + gc] - W[(k + C_CH) * C_CH + gc];
            w1 = W[(k + 1) * C_CH + gc] - W[(k + 1 + C_CH) * C_CH + gc];
        } else {
            int g2 = gc - C_CH;
            w0 = W[(k + C_CH) * C_CH + g2];
            w1 = W[(k + 1 + C_CH) * C_CH + g2];
        }
        unsigned h0 = f2bf_bits(w0), h1 = f2bf_bits(w1);
        float hf0 = __builtin_bit_cast(float, h0 << 16);
        float hf1 = __builtin_bit_cast(float, h1 << 16);
        unsigned l0 = f2bf_bits(w0 - hf0), l1 = f2bf_bits(w1 - hf1);
        *(unsigned*)&Wh[c][k] = h0 | (h1 << 16);
        *(unsigned*)&Wl[c][k] = l0 | (l1 << 16);
    }
    __syncthreads();
    int lane = tid & 63, wv = tid >> 6;
    int r0 = blockIdx.x * 64 + wv * 16;
    int arow = min(r0 + (lane & 15), Nn - 1);
    int kgrp = (lane >> 4) * 8;
    f32x4 acc[4] = {};
#pragma unroll
    for (int kk = 0; kk < 4; ++kk) {
        int k0 = kk * 32 + kgrp;
        const float* xp = &x[(size_t)arow * C_CH + k0];
        float4 v0 = *(const float4*)xp;
        float4 v1 = *(const float4*)(xp + 4);
        float vv[8] = {v0.x, v0.y, v0.z, v0.w, v1.x, v1.y, v1.z, v1.w};
        bf16x8 ah, al;
#pragma unroll
        for (int u = 0; u < 8; ++u) {
            unsigned hb = f2bf_bits(vv[u]);
            float hf = __builtin_bit_cast(float, hb << 16);
            ah[u] = (short)hb;
            al[u] = (short)f2bf_bits(vv[u] - hf);
        }
#pragma unroll
        for (int j = 0; j < 4; ++j) {
            int c = j * 16 + (lane & 15);
            bf16x8 bh = *(const bf16x8*)&Wh[c][k0];
            bf16x8 bl = *(const bf16x8*)&Wl[c][k0];
            acc[j] = __builtin_amdgcn_mfma_f32_16x16x32_bf16(ah, bh, acc[j], 0, 0, 0);
            acc[j] = __builtin_amdgcn_mfma_f32_16x16x32_bf16(al, bh, acc[j], 0, 0, 0);
            acc[j] = __builtin_amdgcn_mfma_f32_16x16x32_bf16(ah, bl, acc[j], 0, 0, 0);
        }
    }
#pragma unroll
    for (int j = 0; j < 4; ++j) {
        int gc = col0 + j * 16 + (lane & 15);
        float badd = isA ? bias[gc] : 0.f;
#pragma unroll
        for (int reg = 0; reg < 4; ++reg) {
            int row = r0 + (lane >> 4) * 4 + reg;  // C/D: col=lane&15, row=(lane>>4)*4+reg
            if (row < Nn) {
                if (isA) Aarr[(size_t)row * C_CH + gc] = acc[j][reg] + badd;
                else     Bbf[(size_t)row * C_CH + (gc - C_CH)] =
                             (unsigned short)f2bf_bits(acc[j][reg]);
            }
        }
    }
}

// ---- K2: per-block bucket histogram -> T2[b][q] (2.5KB LDS, full occupancy) ----
__global__ __launch_bounds__(256) void hist2_k(const int* __restrict__ dst,
                                               int* __restrict__ T2,
                                               int E_, int NBq, int chunk) {
    __shared__ int cnt[BPAD];
    int tid = threadIdx.x, b = blockIdx.x;
    for (int i = tid; i < BPAD; i += 256) cnt[i] = 0;
    __syncthreads();
    int e0 = b * chunk, e1 = min(e0 + chunk, E_);
    int n4 = (e1 - e0) >> 2;
    const int4* d4p = (const int4*)(dst + e0);
    for (int i = tid; i < n4; i += 256) {
        int4 d = d4p[i];
        atomicAdd(&cnt[d.x >> BSH], 1); atomicAdd(&cnt[d.y >> BSH], 1);
        atomicAdd(&cnt[d.z >> BSH], 1); atomicAdd(&cnt[d.w >> BSH], 1);
    }
    for (int i = e0 + n4 * 4 + tid; i < e1; i += 256) atomicAdd(&cnt[dst[i] >> BSH], 1);
    __syncthreads();
    int* Tb = T2 + (size_t)b * BPAD;
    for (int i = tid; i < NBq; i += 256) Tb[i] = cnt[i];
}

// ---- K3: column scan of T2 (HBLK rows), one wave per bucket ----
__global__ __launch_bounds__(256) void colscan2_k(int* __restrict__ T2,
                                                  int* __restrict__ deg2, int NBq) {
    int tid = threadIdx.x;
    int lane = tid & 63;
    int q = blockIdx.x * 4 + (tid >> 6);
    if (q >= NBq) return;  // wave-uniform
    int e[4], p[4];
#pragma unroll
    for (int k = 0; k < 4; ++k) e[k] = T2[(size_t)(lane + 64 * k) * BPAD + q];
    int s = 0;
#pragma unroll
    for (int k = 0; k < 4; ++k) { p[k] = s; s += e[k]; }  // local exclusive
    int incl = s;
#pragma unroll
    for (int off = 1; off < 64; off <<= 1) {
        int t = __shfl_up(incl, off);
        if (lane >= off) incl += t;
    }
    int excl = incl - s;
#pragma unroll
    for (int k = 0; k < 4; ++k) T2[(size_t)(lane + 64 * k) * BPAD + q] = excl + p[k];
    if (lane == 63) deg2[q] = incl;
}

// ---- K4: exclusive prefix sum over deg2 -> offs2 (single block) ----
__global__ __launch_bounds__(1024) void scan_k(const int* __restrict__ deg,
                                               int* __restrict__ offs, int n) {
    __shared__ int wsum[16];
    const int PER = 16;
    int tid = threadIdx.x;
    int base = tid * PER;
    int s = 0;
#pragma unroll
    for (int k = 0; k < PER; ++k) {
        int idx = base + k;
        s += (idx < n) ? deg[idx] : 0;
    }
    int lane = tid & 63, wid = tid >> 6;
    int pref = s;
#pragma unroll
    for (int off = 1; off < 64; off <<= 1) {
        int t = __shfl_up(pref, off);
        if (lane >= off) pref += t;
    }
    if (lane == 63) wsum[wid] = pref;
    __syncthreads();
    if (tid < 16) {
        int v = wsum[tid];
#pragma unroll
        for (int off = 1; off < 16; off <<= 1) {
            int t = __shfl_up(v, off, 16);
            if (tid >= off) v += t;
        }
        wsum[tid] = v;
    }
    __syncthreads();
    int run = ((wid > 0) ? wsum[wid - 1] : 0) + (pref - s);
#pragma unroll
    for (int k = 0; k < PER; ++k) {
        int idx = base + k;
        int v = (idx < n) ? deg[idx] : 0;
        if (idx < n) offs[idx] = run;
        run += v;
    }
    if (tid == 1023) offs[n] = run;
}

// ---- K5: scatter packed (src<<4 | local) into bucket order; 5KB LDS ----
__global__ __launch_bounds__(256) void scatter2_k(const int* __restrict__ src,
                                                  const int* __restrict__ dst,
                                                  const int* __restrict__ T2,
                                                  const int* __restrict__ offs2,
                                                  unsigned* __restrict__ epack,
                                                  int E_, int NBq, int chunk) {
    __shared__ int sbase[BPAD];
    __shared__ int cur[BPAD];
    int tid = threadIdx.x, b = blockIdx.x;
    const int* Tb = T2 + (size_t)b * BPAD;
    for (int i = tid; i < NBq; i += 256) {
        sbase[i] = offs2[i] + Tb[i];
        cur[i] = 0;
    }
    __syncthreads();
    int e0 = b * chunk, e1 = min(e0 + chunk, E_);
    int n4 = (e1 - e0) >> 2;
    const int4* d4p = (const int4*)(dst + e0);
    const int4* s4p = (const int4*)(src + e0);
    const int LM = (1 << BSH) - 1;
    for (int i = tid; i < n4; i += 256) {
        int4 d = d4p[i];
        int4 sv = s4p[i];
        int q, r;
        q = d.x >> BSH; r = atomicAdd(&cur[q], 1);
        epack[sbase[q] + r] = ((unsigned)sv.x << BSH) | (unsigned)(d.x & LM);
        q = d.y >> BSH; r = atomicAdd(&cur[q], 1);
        epack[sbase[q] + r] = ((unsigned)sv.y << BSH) | (unsigned)(d.y & LM);
        q = d.z >> BSH; r = atomicAdd(&cur[q], 1);
        epack[sbase[q] + r] = ((unsigned)sv.z << BSH) | (unsigned)(d.z & LM);
        q = d.w >> BSH; r = atomicAdd(&cur[q], 1);
        epack[sbase[q] + r] = ((unsigned)sv.w << BSH) | (unsigned)(d.w & LM);
    }
    for (int i = e0 + n4 * 4 + tid; i < e1; i += 256) {
        int d = dst[i];
        int q = d >> BSH;
        int r = atomicAdd(&cur[q], 1);
        epack[sbase[q] + r] = ((unsigned)src[i] << BSH) | (unsigned)(d & LM);
    }
}

// ---- K6: per-bucket max (LDS atomicMax on monotonic keys) + fused epilogue ----
// 512 thr = 8 waves; each wave streams 64-edge groups; lane l handles channels
// l and l+64 (2-way bank conflict only). acc[16][128] u32 = 8KB.
__global__ __launch_bounds__(512) void bucket_max(const float* __restrict__ Aarr,
                                                  const unsigned short* __restrict__ Bbf,
                                                  const int* __restrict__ offs2,
                                                  const unsigned* __restrict__ epack,
                                                  float* __restrict__ out, int Nn) {
    int q = blockIdx.x;
    int n0 = q << BSH;
    if (n0 >= Nn) return;
    __shared__ unsigned acc[1 << BSH][C_CH];
    int tid = threadIdx.x;
    int nloc = min(1 << BSH, Nn - n0);
    for (int i = tid; i < (1 << BSH) * C_CH; i += 512) ((unsigned*)acc)[i] = 0u;
    __syncthreads();
    int s = offs2[q], e = offs2[q + 1];
    int lane = tid & 63, w = tid >> 6;
    const int LM = (1 << BSH) - 1;
    for (int g0 = s + w * 64; g0 < e; g0 += 512) {
        int idx = g0 + lane;
        unsigned pk = (idx < e) ? epack[idx] : 0u;
        int cnt = min(64, e - g0);
#pragma unroll 4
        for (int j = 0; j < cnt; ++j) {
            unsigned p = __shfl(pk, j);
            const unsigned short* bp = &Bbf[(size_t)(p >> BSH) * C_CH];
            unsigned loc = p & LM;
            unsigned k0 = mono_key(((unsigned)bp[lane]) << 16);
            unsigned k1 = mono_key(((unsigned)bp[lane + 64]) << 16);
            atomicMax(&acc[loc][lane], k0);
            atomicMax(&acc[loc][lane + 64], k1);
        }
    }
    __syncthreads();
    // epilogue: 4 node-rows per pass (512 thr = 4 x 128 ch)
    for (int p0 = 0; p0 < nloc; p0 += 4) {
        int li = p0 + (tid >> 7);
        int c = tid & 127;
        if (li < nloc) {
            int row = n0 + li;
            unsigned key = acc[li][c];
            float v = 0.f;
            if (key != 0u) {  // key==0 <=> no edge touched this node
                unsigned u = (key & 0x80000000u) ? (key & 0x7FFFFFFFu) : ~key;
                float bmax = __builtin_bit_cast(float, u);
                v = fmaxf(Aarr[(size_t)row * C_CH + c] + bmax, 0.f);
            }
            out[(size_t)row * C_CH + c] = v;
        }
    }
}

extern "C" void kernel_launch(void* const* d_in, const int* in_sizes, int n_in,
                              void* d_out, int out_size, void* d_ws, size_t ws_size,
                              hipStream_t stream) {
    const float* x = (const float*)d_in[0];   // [N,128]
    const float* W = (const float*)d_in[1];   // [256,128]
    const float* b = (const float*)d_in[2];   // [128]
    const int* src = (const int*)d_in[3];     // [E]
    const int* dst = (const int*)d_in[4];     // [E]
    float* out = (float*)d_out;

    const int N = in_sizes[0] / C_CH;
    const int E = in_sizes[3];
    const int NBq = (N + (1 << BSH) - 1) >> BSH;          // buckets (<= BPAD)
    const int chunk = (((E + HBLK - 1) / HBLK) + 3) & ~3;

    char* w = (char*)d_ws;
    float* Aarr = (float*)w;                   w += align_up((size_t)N * C_CH * 4, 256);
    unsigned short* Bbf = (unsigned short*)w;  w += align_up((size_t)N * C_CH * 2, 256);
    int* deg2 = (int*)w;                       w += align_up((size_t)BPAD * 4, 256);
    int* offs2 = (int*)w;                      w += align_up((size_t)(BPAD + 1) * 4, 256);
    int* T2 = (int*)w;                         w += align_up((size_t)HBLK * BPAD * 4, 256);
    unsigned* epack = (unsigned*)w;            w += align_up((size_t)E * 4, 256);

    gemm_mfma<<<dim3((N + 63) / 64, 4), 256, 0, stream>>>(x, W, b, Aarr, Bbf, N);
    hist2_k<<<HBLK, 256, 0, stream>>>(dst, T2, E, NBq, chunk);
    colscan2_k<<<(NBq + 3) / 4, 256, 0, stream>>>(T2, deg2, NBq);
    scan_k<<<1, 1024, 0, stream>>>(deg2, offs2, NBq);
    scatter2_k<<<HBLK, 256, 0, stream>>>(src, dst, T2, offs2, epack, E, NBq, chunk);
    bucket_max<<<NBq, 512, 0, stream>>>(Aarr, Bbf, offs2, epack, out, N);
}

// Round 10
// 118.972 us; speedup vs baseline: 1.2428x; 1.2428x over previous
//
#include <hip/hip_runtime.h>
#include <cstdint>

// EdgeConv on MI355X.
// msg_e = A[dst] + B[src], A = x@(W1-W2)+b, B = x@W2.
// agg[i] = A[i] + max_{e: dst=i} B[src_e];  out = relu(agg), 0 for isolated nodes.
// GEMM: bf16x3 MFMA (fp32-level accuracy), W converted in-block.  [proven R7]
// Bucket CSR (16-node buckets, tiny LDS, full occupancy)  [proven R8]
// bucket_max v2: bucket-local counting sort -> per-node register accumulation.
// NO per-edge LDS atomics / shfl (R8 post-mortem: DS-pipe RMW serialization
// was the 53.6us cost). Per edge: 1 uniform ds_read + 1 coalesced u32 load +
// packed-u16 monotone-key max.

#define C_CH 128
#define HBLK 256          // histogram/scatter blocks
#define BSH 4             // nodes per bucket = 16
#define BPAD 640          // padded bucket count (>= NBq, stride of T2 rows)
#define SCAP 2048         // LDS sort capacity per chunk (mean bucket load 1024)

typedef __attribute__((ext_vector_type(8))) short bf16x8;
typedef __attribute__((ext_vector_type(4))) float f32x4;
typedef __attribute__((ext_vector_type(2))) unsigned short u16x2v;

static inline size_t align_up(size_t v, size_t a) { return (v + a - 1) & ~(a - 1); }

__device__ inline unsigned f2bf_bits(float f) {  // RNE float->bf16 bits
    unsigned u = __builtin_bit_cast(unsigned, f);
    return (u + 0x7FFFu + ((u >> 16) & 1u)) >> 16;
}

// ---- K1: MFMA GEMM. Aarr[N][128] = x@(W1-W2)+b (fp32), Bbf[N][128] = bf16(x@W2).
__global__ __launch_bounds__(256) void gemm_mfma(const float* __restrict__ x,
                                                 const float* __restrict__ W,
                                                 const float* __restrict__ bias,
                                                 float* __restrict__ Aarr,
                                                 unsigned short* __restrict__ Bbf,
                                                 int Nn) {
    __shared__ unsigned short Wh[64][136];
    __shared__ unsigned short Wl[64][136];
    int tid = threadIdx.x;
    int col0 = blockIdx.y * 64;
    bool isA = (col0 < C_CH);  // block-uniform
    for (int idx = tid; idx < 64 * 64; idx += 256) {
        int c = idx & 63, k = (idx >> 6) * 2;
        int gc = col0 + c;
        float w0, w1;
        if (isA) {
            w0 = W[k * C_CH + gc] - W[(k + C_CH) * C_CH + gc];
            w1 = W[(k + 1) * C_CH + gc] - W[(k + 1 + C_CH) * C_CH + gc];
        } else {
            int g2 = gc - C_CH;
            w0 = W[(k + C_CH) * C_CH + g2];
            w1 = W[(k + 1 + C_CH) * C_CH + g2];
        }
        unsigned h0 = f2bf_bits(w0), h1 = f2bf_bits(w1);
        float hf0 = __builtin_bit_cast(float, h0 << 16);
        float hf1 = __builtin_bit_cast(float, h1 << 16);
        unsigned l0 = f2bf_bits(w0 - hf0), l1 = f2bf_bits(w1 - hf1);
        *(unsigned*)&Wh[c][k] = h0 | (h1 << 16);
        *(unsigned*)&Wl[c][k] = l0 | (l1 << 16);
    }
    __syncthreads();
    int lane = tid & 63, wv = tid >> 6;
    int r0 = blockIdx.x * 64 + wv * 16;
    int arow = min(r0 + (lane & 15), Nn - 1);
    int kgrp = (lane >> 4) * 8;
    f32x4 acc[4] = {};
#pragma unroll
    for (int kk = 0; kk < 4; ++kk) {
        int k0 = kk * 32 + kgrp;
        const float* xp = &x[(size_t)arow * C_CH + k0];
        float4 v0 = *(const float4*)xp;
        float4 v1 = *(const float4*)(xp + 4);
        float vv[8] = {v0.x, v0.y, v0.z, v0.w, v1.x, v1.y, v1.z, v1.w};
        bf16x8 ah, al;
#pragma unroll
        for (int u = 0; u < 8; ++u) {
            unsigned hb = f2bf_bits(vv[u]);
            float hf = __builtin_bit_cast(float, hb << 16);
            ah[u] = (short)hb;
            al[u] = (short)f2bf_bits(vv[u] - hf);
        }
#pragma unroll
        for (int j = 0; j < 4; ++j) {
            int c = j * 16 + (lane & 15);
            bf16x8 bh = *(const bf16x8*)&Wh[c][k0];
            bf16x8 bl = *(const bf16x8*)&Wl[c][k0];
            acc[j] = __builtin_amdgcn_mfma_f32_16x16x32_bf16(ah, bh, acc[j], 0, 0, 0);
            acc[j] = __builtin_amdgcn_mfma_f32_16x16x32_bf16(al, bh, acc[j], 0, 0, 0);
            acc[j] = __builtin_amdgcn_mfma_f32_16x16x32_bf16(ah, bl, acc[j], 0, 0, 0);
        }
    }
#pragma unroll
    for (int j = 0; j < 4; ++j) {
        int gc = col0 + j * 16 + (lane & 15);
        float badd = isA ? bias[gc] : 0.f;
#pragma unroll
        for (int reg = 0; reg < 4; ++reg) {
            int row = r0 + (lane >> 4) * 4 + reg;  // C/D: col=lane&15, row=(lane>>4)*4+reg
            if (row < Nn) {
                if (isA) Aarr[(size_t)row * C_CH + gc] = acc[j][reg] + badd;
                else     Bbf[(size_t)row * C_CH + (gc - C_CH)] =
                             (unsigned short)f2bf_bits(acc[j][reg]);
            }
        }
    }
}

// ---- K2: per-block bucket histogram -> T2[b][q] ----
__global__ __launch_bounds__(256) void hist2_k(const int* __restrict__ dst,
                                               int* __restrict__ T2,
                                               int E_, int NBq, int chunk) {
    __shared__ int cnt[BPAD];
    int tid = threadIdx.x, b = blockIdx.x;
    for (int i = tid; i < BPAD; i += 256) cnt[i] = 0;
    __syncthreads();
    int e0 = b * chunk, e1 = min(e0 + chunk, E_);
    int n4 = (e1 - e0) >> 2;
    const int4* d4p = (const int4*)(dst + e0);
    for (int i = tid; i < n4; i += 256) {
        int4 d = d4p[i];
        atomicAdd(&cnt[d.x >> BSH], 1); atomicAdd(&cnt[d.y >> BSH], 1);
        atomicAdd(&cnt[d.z >> BSH], 1); atomicAdd(&cnt[d.w >> BSH], 1);
    }
    for (int i = e0 + n4 * 4 + tid; i < e1; i += 256) atomicAdd(&cnt[dst[i] >> BSH], 1);
    __syncthreads();
    int* Tb = T2 + (size_t)b * BPAD;
    for (int i = tid; i < NBq; i += 256) Tb[i] = cnt[i];
}

// ---- K3: column scan of T2 (HBLK rows), one wave per bucket ----
__global__ __launch_bounds__(256) void colscan2_k(int* __restrict__ T2,
                                                  int* __restrict__ deg2, int NBq) {
    int tid = threadIdx.x;
    int lane = tid & 63;
    int q = blockIdx.x * 4 + (tid >> 6);
    if (q >= NBq) return;  // wave-uniform
    int e[4], p[4];
#pragma unroll
    for (int k = 0; k < 4; ++k) e[k] = T2[(size_t)(lane + 64 * k) * BPAD + q];
    int s = 0;
#pragma unroll
    for (int k = 0; k < 4; ++k) { p[k] = s; s += e[k]; }
    int incl = s;
#pragma unroll
    for (int off = 1; off < 64; off <<= 1) {
        int t = __shfl_up(incl, off);
        if (lane >= off) incl += t;
    }
    int excl = incl - s;
#pragma unroll
    for (int k = 0; k < 4; ++k) T2[(size_t)(lane + 64 * k) * BPAD + q] = excl + p[k];
    if (lane == 63) deg2[q] = incl;
}

// ---- K4: exclusive prefix sum over deg2 -> offs2 (single block) ----
__global__ __launch_bounds__(1024) void scan_k(const int* __restrict__ deg,
                                               int* __restrict__ offs, int n) {
    __shared__ int wsum[16];
    const int PER = 16;
    int tid = threadIdx.x;
    int base = tid * PER;
    int s = 0;
#pragma unroll
    for (int k = 0; k < PER; ++k) {
        int idx = base + k;
        s += (idx < n) ? deg[idx] : 0;
    }
    int lane = tid & 63, wid = tid >> 6;
    int pref = s;
#pragma unroll
    for (int off = 1; off < 64; off <<= 1) {
        int t = __shfl_up(pref, off);
        if (lane >= off) pref += t;
    }
    if (lane == 63) wsum[wid] = pref;
    __syncthreads();
    if (tid < 16) {
        int v = wsum[tid];
#pragma unroll
        for (int off = 1; off < 16; off <<= 1) {
            int t = __shfl_up(v, off, 16);
            if (tid >= off) v += t;
        }
        wsum[tid] = v;
    }
    __syncthreads();
    int run = ((wid > 0) ? wsum[wid - 1] : 0) + (pref - s);
#pragma unroll
    for (int k = 0; k < PER; ++k) {
        int idx = base + k;
        int v = (idx < n) ? deg[idx] : 0;
        if (idx < n) offs[idx] = run;
        run += v;
    }
    if (tid == 1023) offs[n] = run;
}

// ---- K5: scatter packed (src<<4 | local) into bucket order ----
__global__ __launch_bounds__(256) void scatter2_k(const int* __restrict__ src,
                                                  const int* __restrict__ dst,
                                                  const int* __restrict__ T2,
                                                  const int* __restrict__ offs2,
                                                  unsigned* __restrict__ epack,
                                                  int E_, int NBq, int chunk) {
    __shared__ int sbase[BPAD];
    __shared__ int cur[BPAD];
    int tid = threadIdx.x, b = blockIdx.x;
    const int* Tb = T2 + (size_t)b * BPAD;
    for (int i = tid; i < NBq; i += 256) {
        sbase[i] = offs2[i] + Tb[i];
        cur[i] = 0;
    }
    __syncthreads();
    int e0 = b * chunk, e1 = min(e0 + chunk, E_);
    int n4 = (e1 - e0) >> 2;
    const int4* d4p = (const int4*)(dst + e0);
    const int4* s4p = (const int4*)(src + e0);
    const int LM = (1 << BSH) - 1;
    for (int i = tid; i < n4; i += 256) {
        int4 d = d4p[i];
        int4 sv = s4p[i];
        int q, r;
        q = d.x >> BSH; r = atomicAdd(&cur[q], 1);
        epack[sbase[q] + r] = ((unsigned)sv.x << BSH) | (unsigned)(d.x & LM);
        q = d.y >> BSH; r = atomicAdd(&cur[q], 1);
        epack[sbase[q] + r] = ((unsigned)sv.y << BSH) | (unsigned)(d.y & LM);
        q = d.z >> BSH; r = atomicAdd(&cur[q], 1);
        epack[sbase[q] + r] = ((unsigned)sv.z << BSH) | (unsigned)(d.z & LM);
        q = d.w >> BSH; r = atomicAdd(&cur[q], 1);
        epack[sbase[q] + r] = ((unsigned)sv.w << BSH) | (unsigned)(d.w & LM);
    }
    for (int i = e0 + n4 * 4 + tid; i < e1; i += 256) {
        int d = dst[i];
        int q = d >> BSH;
        int r = atomicAdd(&cur[q], 1);
        epack[sbase[q] + r] = ((unsigned)src[i] << BSH) | (unsigned)(d & LM);
    }
}

// ---- K6 v2: bucket-local counting sort + per-node register max + epilogue ----
// 512 thr = 8 waves; wave w owns nodes (2w, 2w+1) of the bucket; lane owns
// channels 2*lane, 2*lane+1 (u32 = 2 bf16). Max kept as packed monotone-u16
// keys (key 0 == "no edge"); no atomics/shfl in the hot loop.
__global__ __launch_bounds__(512) void bucket_max(const float* __restrict__ Aarr,
                                                  const unsigned short* __restrict__ Bbf,
                                                  const int* __restrict__ offs2,
                                                  const unsigned* __restrict__ epack,
                                                  float* __restrict__ out, int Nn) {
    int q = blockIdx.x;
    int n0 = q << BSH;
    if (n0 >= Nn) return;
    __shared__ unsigned sorted[SCAP];
    __shared__ int cnt[1 << BSH], cbase[1 << BSH], cur[1 << BSH];
    int tid = threadIdx.x;
    int lane = tid & 63, w = tid >> 6;
    const int LM = (1 << BSH) - 1;
    int s = offs2[q], e = offs2[q + 1];

    unsigned acc0 = 0u, acc1 = 0u;   // packed u16 keys for node 2w, 2w+1
    int esum0 = 0, esum1 = 0;

    for (int c0 = s; c0 < e; c0 += SCAP) {
        int ccnt = min(SCAP, e - c0);
        // A: 16-entry histogram
        if (tid < (1 << BSH)) cnt[tid] = 0;
        __syncthreads();
        for (int i = tid; i < ccnt; i += 512) atomicAdd(&cnt[epack[c0 + i] & LM], 1);
        __syncthreads();
        // B: serial 16-scan (thread 0)
        if (tid == 0) {
            int r = 0;
#pragma unroll
            for (int k = 0; k < (1 << BSH); ++k) { cbase[k] = r; r += cnt[k]; }
        }
        __syncthreads();
        if (tid < (1 << BSH)) cur[tid] = cbase[tid];
        __syncthreads();
        // C: scatter into sorted[] (node-grouped)
        for (int i = tid; i < ccnt; i += 512) {
            unsigned p = epack[c0 + i];
            int r = atomicAdd(&cur[p & LM], 1);
            sorted[r] = p;
        }
        __syncthreads();
        // D: per-wave register max over the two owned segments
#pragma unroll
        for (int sub = 0; sub < 2; ++sub) {
            int loc = 2 * w + sub;
            int ss = cbase[loc], ee = cbase[loc] + cnt[loc];
            unsigned a = (sub == 0) ? acc0 : acc1;
            for (int j = ss; j < ee; j += 8) {
                unsigned wv[8];
#pragma unroll
                for (int u = 0; u < 8; ++u) {
                    int idx = min(j + u, ee - 1);          // clamp dup: max-safe
                    unsigned row = sorted[idx] >> BSH;     // uniform ds_read
                    wv[u] = *(const unsigned*)&Bbf[(size_t)row * C_CH + 2 * lane];
                }
#pragma unroll
                for (int u = 0; u < 8; ++u) {
                    unsigned uu = wv[u];
                    unsigned sgn = (uu >> 15) & 0x00010001u;
                    unsigned key = uu ^ (0x80008000u | (sgn * 0x7FFFu));
                    u16x2v av = __builtin_bit_cast(u16x2v, a);
                    u16x2v kv = __builtin_bit_cast(u16x2v, key);
                    a = __builtin_bit_cast(unsigned, __builtin_elementwise_max(av, kv));
                }
            }
            if (sub == 0) { acc0 = a; esum0 += cnt[loc]; }
            else          { acc1 = a; esum1 += cnt[loc]; }
        }
        __syncthreads();  // protect cnt/cbase/sorted before next chunk
    }

    // epilogue: each wave writes its 2 node rows (float2 per lane, coalesced)
#pragma unroll
    for (int sub = 0; sub < 2; ++sub) {
        int row = n0 + 2 * w + sub;
        if (row >= Nn) continue;
        unsigned a = (sub == 0) ? acc0 : acc1;
        int es = (sub == 0) ? esum0 : esum1;
        float2 o = make_float2(0.f, 0.f);
        if (es > 0) {
            // decode packed keys -> bf16 bits: h = k15 ? k^0x8000 : ~k (per half)
            unsigned t = (a >> 15) & 0x00010001u;
            unsigned h = a ^ (0xFFFFFFFFu - t * 0x7FFFu);
            float blo = __builtin_bit_cast(float, (h & 0xFFFFu) << 16);
            float bhi = __builtin_bit_cast(float, h & 0xFFFF0000u);
            const float2 av = *(const float2*)&Aarr[(size_t)row * C_CH + 2 * lane];
            o.x = fmaxf(av.x + blo, 0.f);
            o.y = fmaxf(av.y + bhi, 0.f);
        }
        *(float2*)&out[(size_t)row * C_CH + 2 * lane] = o;
    }
}

extern "C" void kernel_launch(void* const* d_in, const int* in_sizes, int n_in,
                              void* d_out, int out_size, void* d_ws, size_t ws_size,
                              hipStream_t stream) {
    const float* x = (const float*)d_in[0];   // [N,128]
    const float* W = (const float*)d_in[1];   // [256,128]
    const float* b = (const float*)d_in[2];   // [128]
    const int* src = (const int*)d_in[3];     // [E]
    const int* dst = (const int*)d_in[4];     // [E]
    float* out = (float*)d_out;

    const int N = in_sizes[0] / C_CH;
    const int E = in_sizes[3];
    const int NBq = (N + (1 << BSH) - 1) >> BSH;
    const int chunk = (((E + HBLK - 1) / HBLK) + 3) & ~3;

    char* w = (char*)d_ws;
    float* Aarr = (float*)w;                   w += align_up((size_t)N * C_CH * 4, 256);
    unsigned short* Bbf = (unsigned short*)w;  w += align_up((size_t)N * C_CH * 2, 256);
    int* deg2 = (int*)w;                       w += align_up((size_t)BPAD * 4, 256);
    int* offs2 = (int*)w;                      w += align_up((size_t)(BPAD + 1) * 4, 256);
    int* T2 = (int*)w;                         w += align_up((size_t)HBLK * BPAD * 4, 256);
    unsigned* epack = (unsigned*)w;            w += align_up((size_t)E * 4, 256);

    gemm_mfma<<<dim3((N + 63) / 64, 4), 256, 0, stream>>>(x, W, b, Aarr, Bbf, N);
    hist2_k<<<HBLK, 256, 0, stream>>>(dst, T2, E, NBq, chunk);
    colscan2_k<<<(NBq + 3) / 4, 256, 0, stream>>>(T2, deg2, NBq);
    scan_k<<<1, 1024, 0, stream>>>(deg2, offs2, NBq);
    scatter2_k<<<HBLK, 256, 0, stream>>>(src, dst, T2, offs2, epack, E, NBq, chunk);
    bucket_max<<<NBq, 512, 0, stream>>>(Aarr, Bbf, offs2, epack, out, N);
}